// Round 2
// baseline (999.618 us; speedup 1.0000x reference)
//
#include <hip/hip_runtime.h>
#include <math.h>

// Problem constants
#define T_TOKENS 32768
#define DIM      2048
#define NEXP     256
#define NGROUP   8
#define GSIZE    32
#define TOPG     4
#define TOPK     8
#define SCALE    2.5

// Tiling
#define BM 64
#define BK 32
#define NKT (DIM / BK)       // 64 k-tiles
// LDS strides in doubles
#define AS_STRIDE 66         // 64 + 2
#define BS_STRIDE 257        // 256 + 1 (keeps ds offset imm < 64KB, odd stride)
#define SC_STRIDE 257

#define AS_BASE 0
#define BS_BASE (BK * AS_STRIDE)            // 2112
// Bs end: 2112 + 32*257 = 10336  <= 16448 (Sc region size) -> union is safe

__global__ __launch_bounds__(256, 1) void nemotron_router_kernel(
    const float* __restrict__ H,     // [T, D] fp32
    const float* __restrict__ Wt,    // [E, D] fp32
    const float* __restrict__ bias,  // [E]    fp32
    float* __restrict__ out)         // [T*8 idx as float][T*8 weights]
{
    // Union: {As f64 [BK][AS_STRIDE], Bs f64 [BK][BS_STRIDE]} then Sc f64 [BM][SC_STRIDE]
    __shared__ double smem[BM * SC_STRIDE];   // 131584 B
    __shared__ double biasD[NEXP];            // 2048 B

    const int tid = threadIdx.x;
    const int t0  = blockIdx.x * BM;

    biasD[tid] = (double)bias[tid];

    // compute-phase mapping: 8 rows x 8 strided experts per thread
    const int c0 = tid & 31;            // expert base; experts c0 + 32*j  (j = group)
    const int r0 = (tid >> 5) * 8;      // token rows r0..r0+7

    // staging mapping
    const int arow = tid >> 2;          // 0..63
    const int acol = (tid & 3) * 8;     // 0,8,16,24
    const float* Aptr = H + (size_t)(t0 + arow) * DIM + acol;
    const float* Bptr = Wt + (size_t)tid * DIM;   // expert == tid

    double acc[8][8];
    #pragma unroll
    for (int i = 0; i < 8; ++i)
        #pragma unroll
        for (int j = 0; j < 8; ++j)
            acc[i][j] = 0.0;

    // prefetch tile 0 into registers
    float4 ra0 = *(const float4*)(Aptr + 0);
    float4 ra1 = *(const float4*)(Aptr + 4);
    float4 rb[8];
    #pragma unroll
    for (int q = 0; q < 8; ++q) rb[q] = *(const float4*)(Bptr + q * 4);

    for (int kt = 0; kt < NKT; ++kt) {
        __syncthreads();   // previous tile's LDS reads complete

        // --- write staged registers -> LDS as f64, k-major ---
        {
            const float a[8] = {ra0.x, ra0.y, ra0.z, ra0.w, ra1.x, ra1.y, ra1.z, ra1.w};
            #pragma unroll
            for (int m = 0; m < 8; ++m)
                smem[AS_BASE + (acol + m) * AS_STRIDE + arow] = (double)a[m];
        }
        #pragma unroll
        for (int q = 0; q < 8; ++q) {
            smem[BS_BASE + (q * 4 + 0) * BS_STRIDE + tid] = (double)rb[q].x;
            smem[BS_BASE + (q * 4 + 1) * BS_STRIDE + tid] = (double)rb[q].y;
            smem[BS_BASE + (q * 4 + 2) * BS_STRIDE + tid] = (double)rb[q].z;
            smem[BS_BASE + (q * 4 + 3) * BS_STRIDE + tid] = (double)rb[q].w;
        }
        __syncthreads();

        // --- prefetch next tile (overlaps with compute below) ---
        if (kt + 1 < NKT) {
            const int k1 = (kt + 1) * BK;
            ra0 = *(const float4*)(Aptr + k1);
            ra1 = *(const float4*)(Aptr + k1 + 4);
            #pragma unroll
            for (int q = 0; q < 8; ++q) rb[q] = *(const float4*)(Bptr + k1 + q * 4);
        }

        // --- fp64 compute: 8x8 micro-tile ---
        #pragma unroll 4
        for (int kk = 0; kk < BK; ++kk) {
            double a[8], b[8];
            #pragma unroll
            for (int m = 0; m < 8; ++m)
                a[m] = smem[AS_BASE + kk * AS_STRIDE + r0 + m];
            #pragma unroll
            for (int j = 0; j < 8; ++j)
                b[j] = smem[BS_BASE + kk * BS_STRIDE + c0 + 32 * j];
            #pragma unroll
            for (int i = 0; i < 8; ++i)
                #pragma unroll
                for (int j = 0; j < 8; ++j)
                    acc[i][j] = fma(a[i], b[j], acc[i][j]);
        }
    }

    __syncthreads();   // all As/Bs reads done before Sc overwrite (aliased)

    // --- store fp64 logits to Sc ---
    #pragma unroll
    for (int i = 0; i < 8; ++i)
        #pragma unroll
        for (int j = 0; j < 8; ++j)
            smem[(r0 + i) * SC_STRIDE + (c0 + 32 * j)] = acc[i][j];
    __syncthreads();

    // --- router: one thread per token, all decisions in fp64 ---
    if (tid < BM) {
        double* row = &smem[tid * SC_STRIDE];

        // group scores: top-2 logits per group (bias is uniform -> biased order
        // == sigmoid order == logit order), then fp64 sigmoid + bias, summed
        // in descending order exactly like top_k(...,2).sum(-1).
        double gs[NGROUP];
        for (int g = 0; g < NGROUP; ++g) {
            const int base = g * GSIZE;
            double m1 = -1e300, m2 = -1e300;
            for (int j = 0; j < GSIZE; ++j) {
                const double l = row[base + j];
                if (l > m1) { m2 = m1; m1 = l; }
                else if (l > m2) { m2 = l; }
            }
            const double v1 = 1.0 / (1.0 + exp(-m1)) + biasD[base];
            const double v2 = 1.0 / (1.0 + exp(-m2)) + biasD[base];
            gs[g] = v1 + v2;
        }

        // top-4 groups (ties -> lower index)
        unsigned gsel = 0;
        for (int g = 0; g < NGROUP; ++g) {
            int rank = 0;
            for (int h = 0; h < NGROUP; ++h)
                rank += (gs[h] > gs[g]) || (gs[h] == gs[g] && h < g);
            if (rank < TOPG) gsel |= 1u << g;
        }

        // overwrite allowed-group logits with fp64 biased sigmoid values
        for (int g = 0; g < NGROUP; ++g) {
            if (!((gsel >> g) & 1u)) continue;
            const int base = g * GSIZE;
            for (int j = 0; j < GSIZE; ++j) {
                const int e = base + j;
                row[e] = 1.0 / (1.0 + exp(-row[e])) + biasD[e];
            }
        }

        // top-8 experts by biased sigmoid, descending; strict > with ascending
        // scan reproduces top_k tie-breaking (lower index first).
        double wsel[TOPK];
        int    isel[TOPK];
        double wsum = 0.0;
        for (int k = 0; k < TOPK; ++k) {
            double best = -1e300;
            int    bi   = 0;
            for (int g = 0; g < NGROUP; ++g) {
                if (!((gsel >> g) & 1u)) continue;
                const int base = g * GSIZE;
                for (int j = 0; j < GSIZE; ++j) {
                    const int e = base + j;
                    const double v = row[e];
                    if (v > best) { best = v; bi = e; }
                }
            }
            const double w = row[bi] - biasD[bi];   // un-biased sigmoid (±1 ulp)
            wsel[k] = w;
            isel[k] = bi;
            wsum   += w;
            row[bi] = -1e300;
        }

        const double norm = SCALE / wsum;
        const size_t t = (size_t)(t0 + tid);
        float* oi = out + t * TOPK;
        float* ow = out + (size_t)T_TOKENS * TOPK + t * TOPK;
        #pragma unroll
        for (int k = 0; k < TOPK; ++k) {
            oi[k] = (float)isel[k];
            ow[k] = (float)(wsel[k] * norm);
        }
    }
}

extern "C" void kernel_launch(void* const* d_in, const int* in_sizes, int n_in,
                              void* d_out, int out_size, void* d_ws, size_t ws_size,
                              hipStream_t stream) {
    const float* H    = (const float*)d_in[0];  // [32768, 2048]
    const float* Wt   = (const float*)d_in[1];  // [256, 2048]
    const float* bias = (const float*)d_in[2];  // [256]
    float* out = (float*)d_out;

    dim3 grid(T_TOKENS / BM);   // 512
    dim3 block(256);
    nemotron_router_kernel<<<grid, block, 0, stream>>>(H, Wt, bias, out);
}